// Round 3
// baseline (810.055 us; speedup 1.0000x reference)
//
#include <hip/hip_runtime.h>
#include <hip/hip_bf16.h>
#include <cfloat>

// ---------------------------------------------------------------------------
// CrossVectorAttentionEncoder on MI355X (gfx950)
// Pipeline:
//   k_norms   : ||src||^2 per (b,ns)
//   k_sp      : sp_all = src_pos @ up_src_w + up_src_b   (affine in 2 scalars)
//   k_prep    : pack psi|alpha weight (fp32), transpose+bf16+swizzle MLP weights
//   gemm(dot) : dot = tgt . src^T (fp32, exact-enough for top-k ordering)
//   k_topk    : 16 smallest (snorm - 2*dot) per row -> idx
//   gemm(pa)  : pa_all = src_heads @ [psi_w|alpha_w] + bias (all NS, pre-gather)
//   gemm(phi) : phi_all = tgt_heads @ phi_w + phi_b
//   k_delta   : per (b,nt): Xd=tp-sp(gather) -> MFMA MLP -> delta; emits
//               gin = phi - psi + delta (bf16, pre-swizzled), val = alp + delta
//   k_gamma   : per (b,nt): MFMA MLP on gin -> logits -> softmax over K ->
//               out = sum_k attn*val
//   k_ln      : x = LN(tgt + out)
//   gemm x2   : FFN (fp32)
//   k_ln      : out = LN(x + ffn)
// ---------------------------------------------------------------------------

#define DEVINL __device__ __forceinline__

constexpr int B_   = 2;
constexpr int NT   = 1024;
constexpr int NS   = 4096;
constexpr int DM   = 512;
constexpr int H    = 8;
constexpr int KNN  = 16;
constexpr int DH   = 64;
constexpr int DFF  = 2048;

typedef float f32x4 __attribute__((ext_vector_type(4)));
typedef short s16x8 __attribute__((ext_vector_type(8)));
typedef short s16x4 __attribute__((ext_vector_type(4)));

DEVINL short f2b(float f) {
    __hip_bfloat16 h = __float2bfloat16(f);
    short s; __builtin_memcpy(&s, &h, 2); return s;
}
DEVINL float b2f(short s) {
    __hip_bfloat16 h; __builtin_memcpy(&h, &s, 2); return __bfloat162float(h);
}
DEVINL f32x4 mfma16(s16x8 a, s16x8 b, f32x4 c) {
    return __builtin_amdgcn_mfma_f32_16x16x32_bf16(a, b, c, 0, 0, 0);
}

// ---------------------------------------------------------------------------
// ||row||^2 for rows of length DM. one wave per row.
__global__ __launch_bounds__(256) void k_norms(const float* __restrict__ x,
                                               float* __restrict__ nrm, int rows) {
    const int w = threadIdx.x >> 6, l = threadIdx.x & 63;
    const int row = blockIdx.x * 4 + w;
    if (row >= rows) return;
    const f32x4* p4 = (const f32x4*)(x + (size_t)row * DM);
    f32x4 v0 = p4[l], v1 = p4[l + 64];
    float acc = v0.x*v0.x + v0.y*v0.y + v0.z*v0.z + v0.w*v0.w
              + v1.x*v1.x + v1.y*v1.y + v1.z*v1.z + v1.w*v1.w;
    #pragma unroll
    for (int off = 32; off >= 1; off >>= 1) acc += __shfl_xor(acc, off);
    if (l == 0) nrm[row] = acc;
}

// ---------------------------------------------------------------------------
// sp_all[b][ns][c] = p0*W[0][c] + p1*W[1][c] + ub[c]
__global__ __launch_bounds__(256) void k_sp(const float* __restrict__ src_pos,
                                            const float* __restrict__ upw,
                                            const float* __restrict__ upb,
                                            float* __restrict__ sp) {
    const int i = blockIdx.x * 256 + threadIdx.x;  // f32x4 index
    if (i >= B_ * NS * DM / 4) return;
    const int c4 = i & (DM / 4 - 1);
    const int bn = i >> 7;
    const float p0 = src_pos[bn * 2 + 0], p1 = src_pos[bn * 2 + 1];
    f32x4 w0 = ((const f32x4*)upw)[c4];
    f32x4 w1 = ((const f32x4*)upw)[DM / 4 + c4];
    f32x4 ub = ((const f32x4*)upb)[c4];
    f32x4 r;
    r.x = p0 * w0.x + p1 * w1.x + ub.x;
    r.y = p0 * w0.y + p1 * w1.y + ub.y;
    r.z = p0 * w0.z + p1 * w1.z + ub.z;
    r.w = p0 * w0.w + p1 * w1.w + ub.w;
    ((f32x4*)sp)[i] = r;
}

// ---------------------------------------------------------------------------
// weight prep: pack [psi_w|alpha_w] fp32; transpose+bf16+XOR-swizzle the 4 MLP
// weights so kernels can stage linearly and read b128 frags conflict-free.
// layout: Wt[n][ k ^ ((n&7)<<3) ] = W[k][n]
__global__ __launch_bounds__(256) void k_prep(
    const float* __restrict__ psi_w, const float* __restrict__ psi_b,
    const float* __restrict__ alpha_w, const float* __restrict__ alpha_b,
    const float* __restrict__ th_w1, const float* __restrict__ th_w2,
    const float* __restrict__ ga_w1, const float* __restrict__ ga_w2,
    float* __restrict__ Wpa, float* __restrict__ bias_pa,
    short* __restrict__ thw1t, short* __restrict__ thw2t,
    short* __restrict__ gaw1t, short* __restrict__ gaw2t) {
    int i = blockIdx.x * 256 + threadIdx.x;
    if (i < 8192) { int k = i >> 7, j = i & 127;
        Wpa[i] = (j < 64) ? psi_w[k * 64 + j] : alpha_w[k * 64 + (j - 64)]; return; }
    i -= 8192;
    if (i < 128) { bias_pa[i] = (i < 64) ? psi_b[i] : alpha_b[i - 64]; return; }
    i -= 128;
    if (i < 16384) { int n = i >> 6, k = i & 63;
        thw1t[(n << 6) + (k ^ ((n & 7) << 3))] = f2b(th_w1[k * 256 + n]); return; }
    i -= 16384;
    if (i < 16384) { int n = i >> 8, k = i & 255;
        thw2t[(n << 8) + (k ^ ((n & 7) << 3))] = f2b(th_w2[k * 64 + n]); return; }
    i -= 16384;
    if (i < 16384) { int n = i >> 6, k = i & 63;
        gaw1t[(n << 6) + (k ^ ((n & 7) << 3))] = f2b(ga_w1[k * 256 + n]); return; }
    i -= 16384;
    if (i < 16384) { int n = i >> 8, k = i & 255;
        gaw2t[(n << 8) + (k ^ ((n & 7) << 3))] = f2b(ga_w2[k * 64 + n]); return; }
}

// ---------------------------------------------------------------------------
// fp32 GEMM, BM=128, BK=16, BN in {64,128}. C = op(A@B + bias).
// TRANSB: B given as [N][K] row-major (for A.B^T). LDS tiles stored k-major.
// TN==8 micro-tile columns are split {tn*4, 64+tn*4}: consecutive lanes read
// consecutive 16B LDS slots -> 2-way bank aliasing (free) instead of 4-way.
template <int BN, bool TRANSB, bool RELU, bool HASBIAS>
__global__ __launch_bounds__(256) void k_gemm_f32(
    const float* __restrict__ A, int lda, long sA,
    const float* __restrict__ Bm, int ldb, long sB,
    float* __restrict__ C, int ldc, long sC,
    const float* __restrict__ bias, int K) {
    constexpr int BM = 128, BK = 16;
    constexpr int TN = BN / 16;
    __shared__ float As[BK][BM];
    __shared__ float Bs[BK][BN];
    A  += (size_t)blockIdx.z * sA;
    Bm += (size_t)blockIdx.z * sB;
    C  += (size_t)blockIdx.z * sC;
    const int m0 = blockIdx.y * BM, n0 = blockIdx.x * BN;
    const int tid = threadIdx.x, tm = tid >> 4, tn = tid & 15;
    float acc[8][TN];
    #pragma unroll
    for (int i = 0; i < 8; i++)
        #pragma unroll
        for (int j = 0; j < TN; j++) acc[i][j] = 0.f;

    for (int k0 = 0; k0 < K; k0 += BK) {
        {   // stage A (transposed): As[k][m]
            const int m = tid >> 1;
            #pragma unroll
            for (int i = 0; i < 2; i++) {
                const int kq = (tid & 1) * 2 + i;
                f32x4 v = *(const f32x4*)(A + (size_t)(m0 + m) * lda + k0 + kq * 4);
                As[kq * 4 + 0][m] = v.x; As[kq * 4 + 1][m] = v.y;
                As[kq * 4 + 2][m] = v.z; As[kq * 4 + 3][m] = v.w;
            }
        }
        if constexpr (TRANSB) {
            if constexpr (BN == 128) {
                const int n = tid >> 1;
                #pragma unroll
                for (int i = 0; i < 2; i++) {
                    const int kq = (tid & 1) * 2 + i;
                    f32x4 v = *(const f32x4*)(Bm + (size_t)(n0 + n) * ldb + k0 + kq * 4);
                    Bs[kq * 4 + 0][n] = v.x; Bs[kq * 4 + 1][n] = v.y;
                    Bs[kq * 4 + 2][n] = v.z; Bs[kq * 4 + 3][n] = v.w;
                }
            } else {
                const int n = tid >> 2, kq = tid & 3;
                f32x4 v = *(const f32x4*)(Bm + (size_t)(n0 + n) * ldb + k0 + kq * 4);
                Bs[kq * 4 + 0][n] = v.x; Bs[kq * 4 + 1][n] = v.y;
                Bs[kq * 4 + 2][n] = v.z; Bs[kq * 4 + 3][n] = v.w;
            }
        } else {
            if constexpr (BN == 128) {
                const int kr = tid >> 5, nq = tid & 31;
                #pragma unroll
                for (int i = 0; i < 2; i++)
                    *(f32x4*)&Bs[kr + i * 8][nq * 4] =
                        *(const f32x4*)(Bm + (size_t)(k0 + kr + i * 8) * ldb + n0 + nq * 4);
            } else {
                const int kr = tid >> 4, nq = tid & 15;
                *(f32x4*)&Bs[kr][nq * 4] =
                    *(const f32x4*)(Bm + (size_t)(k0 + kr) * ldb + n0 + nq * 4);
            }
        }
        __syncthreads();
        #pragma unroll
        for (int d = 0; d < BK; d++) {
            float ar[8], br[TN];
            *(f32x4*)&ar[0] = *(const f32x4*)&As[d][tm * 8];      // broadcast (free)
            *(f32x4*)&ar[4] = *(const f32x4*)&As[d][tm * 8 + 4];
            *(f32x4*)&br[0] = *(const f32x4*)&Bs[d][tn * 4];
            if constexpr (TN == 8) *(f32x4*)&br[4] = *(const f32x4*)&Bs[d][64 + tn * 4];
            #pragma unroll
            for (int i = 0; i < 8; i++)
                #pragma unroll
                for (int j = 0; j < TN; j++)
                    acc[i][j] = fmaf(ar[i], br[j], acc[i][j]);
        }
        __syncthreads();
    }
    #pragma unroll
    for (int i = 0; i < 8; i++) {
        const int m = m0 + tm * 8 + i;
        float* crow = C + (size_t)m * ldc + n0;
        #pragma unroll
        for (int j = 0; j < TN; j++) {
            const int c = (TN == 8) ? ((j < 4) ? tn * 4 + j : 64 + tn * 4 + (j - 4))
                                    : tn * 4 + j;
            float v = acc[i][j];
            if constexpr (HASBIAS) v += bias[n0 + c];
            if constexpr (RELU) v = fmaxf(v, 0.f);
            acc[i][j] = v;
        }
        *(f32x4*)(crow + tn * 4) = *(f32x4*)&acc[i][0];
        if constexpr (TN == 8) *(f32x4*)(crow + 64 + tn * 4) = *(f32x4*)&acc[i][4];
    }
}

// ---------------------------------------------------------------------------
// top-16 smallest (snorm[n] - 2*dot[row][n]) per row. one block per row.
// wave-level shfl reduction (2 barriers/round instead of 8).
__global__ __launch_bounds__(256) void k_topk(const float* __restrict__ dotm,
                                              const float* __restrict__ snorm,
                                              int* __restrict__ idx_out) {
    __shared__ float vals[NS];
    __shared__ float wv_[4];
    __shared__ int   wi_[4];
    const int row = blockIdx.x;           // b*NT + m
    const int b = row >> 10;
    const int tid = threadIdx.x, l = tid & 63, w = tid >> 6;
    {
        const f32x4* d4 = (const f32x4*)(dotm + (size_t)row * NS);
        const f32x4* s4 = (const f32x4*)(snorm + (size_t)b * NS);
        #pragma unroll
        for (int t = 0; t < NS / 4 / 256; t++) {
            const int i = tid + t * 256;
            f32x4 dv = d4[i], sv = s4[i];
            f32x4 r;
            r.x = sv.x - 2.f * dv.x; r.y = sv.y - 2.f * dv.y;
            r.z = sv.z - 2.f * dv.z; r.w = sv.w - 2.f * dv.w;
            *(f32x4*)&vals[i * 4] = r;
        }
    }
    __syncthreads();
    for (int r = 0; r < KNN; r++) {
        float best = FLT_MAX; int bi = 0x7fffffff;
        #pragma unroll
        for (int t = 0; t < NS / 256; t++) {
            const int i = tid + t * 256;
            const float v = vals[i];
            if (v < best) { best = v; bi = i; }   // ascending i: first hit = lowest idx
        }
        #pragma unroll
        for (int off = 32; off >= 1; off >>= 1) {
            const float ov = __shfl_xor(best, off);
            const int   oi = __shfl_xor(bi, off);
            if (ov < best || (ov == best && oi < bi)) { best = ov; bi = oi; }
        }
        if (l == 0) { wv_[w] = best; wi_[w] = bi; }
        __syncthreads();
        if (tid == 0) {
            float bb = wv_[0]; int bbi = wi_[0];
            #pragma unroll
            for (int j = 1; j < 4; j++)
                if (wv_[j] < bb || (wv_[j] == bb && wi_[j] < bbi)) { bb = wv_[j]; bbi = wi_[j]; }
            idx_out[row * KNN + r] = bbi;
            vals[bbi] = FLT_MAX;
        }
        __syncthreads();
    }
}

// ---------------------------------------------------------------------------
// delta MLP per (b,nt): Xd = tp - sp(gather); hid = relu(Xd@th_w1+b1);
// delta = hid@th_w2+b2; emit gin = phi - psi + delta (bf16, swizzled rows)
// and val = alp + delta (bf16, linear). Writeback staged through LDS (reusing
// Hd after its last read) so global stores are coalesced f32x4.
__global__ __launch_bounds__(256) void k_delta(
    const float* __restrict__ tgt_pos, const float* __restrict__ sp_all,
    const float* __restrict__ phi_all, const float* __restrict__ pa_all,
    const int* __restrict__ idx_in,
    const short* __restrict__ w1t, const short* __restrict__ w2t,
    const float* __restrict__ b1v, const float* __restrict__ b2vv,
    short* __restrict__ gin_ws, short* __restrict__ val_ws) {
    __shared__ alignas(16) short W1[256 * 64];
    __shared__ alignas(16) short W2[64 * 256];
    __shared__ alignas(16) short Xd[16 * 64];
    __shared__ alignas(16) short Hd[16 * 256];
    __shared__ float B1s[256];
    __shared__ int sidx[16];
    const int bn = blockIdx.x;
    const int b = bn >> 10;
    const int tid = threadIdx.x;
    const int w = tid >> 6, l = tid & 63;
    {
        const f32x4* s1 = (const f32x4*)w1t; f32x4* d1 = (f32x4*)W1;
        const f32x4* s2 = (const f32x4*)w2t; f32x4* d2 = (f32x4*)W2;
        #pragma unroll
        for (int i = 0; i < 8; i++) {
            d1[tid + i * 256] = s1[tid + i * 256];
            d2[tid + i * 256] = s2[tid + i * 256];
        }
    }
    B1s[tid] = b1v[tid];
    if (tid < 16) sidx[tid] = idx_in[bn * KNN + tid];
    __syncthreads();
    const float* tp_row = tgt_pos + (size_t)bn * DM;
    const int col = l & 15, lg = l >> 4;
    for (int h = 0; h < H; h++) {
        {   // build Xd[16][64] = tp - sp, bf16, swizzled (vectorized)
            const int k = tid >> 4, e0 = (tid & 15) << 2;
            const float* sp_row = sp_all + ((size_t)(b * NS) + sidx[k]) * DM + h * DH;
            const f32x4 tpv = *(const f32x4*)(tp_row + h * DH + e0);
            const f32x4 spv = *(const f32x4*)(sp_row + e0);
            s16x4 o;
            o[0] = f2b(tpv.x - spv.x); o[1] = f2b(tpv.y - spv.y);
            o[2] = f2b(tpv.z - spv.z); o[3] = f2b(tpv.w - spv.w);
            *(s16x4*)&Xd[(k << 6) + (e0 ^ ((k & 7) << 3))] = o;
        }
        __syncthreads();                                   // (1)
        {   // GEMM1: Hd[16][256] = relu(Xd @ th_w1 + b1), bf16
            const s16x8 a0 = *(const s16x8*)&Xd[(col << 6) + ((lg * 8) ^ ((col & 7) << 3))];
            const s16x8 a1 = *(const s16x8*)&Xd[(col << 6) + ((32 + lg * 8) ^ ((col & 7) << 3))];
            f32x4 acc[4];
            #pragma unroll
            for (int t = 0; t < 4; t++) acc[t] = f32x4{0.f, 0.f, 0.f, 0.f};
            #pragma unroll
            for (int t = 0; t < 4; t++) {
                const int n = (w << 6) + (t << 4) + col;
                const s16x8 bb0 = *(const s16x8*)&W1[(n << 6) + ((lg * 8) ^ ((n & 7) << 3))];
                const s16x8 bb1 = *(const s16x8*)&W1[(n << 6) + ((32 + lg * 8) ^ ((n & 7) << 3))];
                acc[t] = mfma16(a0, bb0, acc[t]);
                acc[t] = mfma16(a1, bb1, acc[t]);
            }
            #pragma unroll
            for (int t = 0; t < 4; t++) {
                const int n = (w << 6) + (t << 4) + col;
                const float bb = B1s[n];
                #pragma unroll
                for (int r = 0; r < 4; r++) {
                    const int kr = (lg << 2) + r;
                    Hd[(kr << 8) + (n ^ ((kr & 7) << 3))] = f2b(fmaxf(acc[t][r] + bb, 0.f));
                }
            }
        }
        __syncthreads();                                   // (2)
        // GEMM2: delta[16][64] = Hd @ th_w2 + b2 ; gin/val staged in LDS
        f32x4 acc = f32x4{0.f, 0.f, 0.f, 0.f};
        const int n = (w << 4) + col;   // output channel d
        #pragma unroll
        for (int kt = 0; kt < 8; kt++) {
            const int el = kt * 32 + lg * 8;
            const s16x8 a  = *(const s16x8*)&Hd[(col << 8) + (el ^ ((col & 7) << 3))];
            const s16x8 bb = *(const s16x8*)&W2[(n << 8) + (el ^ ((n & 7) << 3))];
            acc = mfma16(a, bb, acc);
        }
        __syncthreads();                                   // (3) all Hd reads done
        {
            short* Gs = Hd;            // [16][64] swizzled gin  (2 KB)
            short* Vs = Hd + 1024;     // [16][64] linear   val  (2 KB)
            const float b2v = b2vv[n];
            const float phiv = phi_all[(size_t)bn * DM + h * DH + n];
            #pragma unroll
            for (int r = 0; r < 4; r++) {
                const int k = (lg << 2) + r;
                const float* pa = pa_all + (((size_t)(b * NS) + sidx[k]) * H + h) * 128;
                const float delta = acc[r] + b2v;
                Gs[(k << 6) + (n ^ ((k & 7) << 3))] = f2b(phiv - pa[n] + delta);
                Vs[(k << 6) + n] = f2b(pa[64 + n] + delta);
            }
        }
        __syncthreads();                                   // (4)
        {   // coalesced copy-out: 2 KB gin + 2 KB val per head
            const size_t obase = ((size_t)bn * H + h) * (KNN * DH); // in shorts
            if (tid < 128)
                ((f32x4*)(gin_ws + obase))[tid] = ((const f32x4*)Hd)[tid];
            else
                ((f32x4*)(val_ws + obase))[tid - 128] = ((const f32x4*)(Hd + 1024))[tid - 128];
        }
        __syncthreads();                                   // (5) = loop barrier
    }
}

// ---------------------------------------------------------------------------
// gamma MLP + softmax-over-K + weighted sum. one block per (b,nt).
__global__ __launch_bounds__(256) void k_gamma(
    const short* __restrict__ gin_ws, const short* __restrict__ val_ws,
    const short* __restrict__ w1t, const short* __restrict__ w2t,
    const float* __restrict__ b1v, const float* __restrict__ b2vv,
    float* __restrict__ attn_o) {
    __shared__ alignas(16) short W1[256 * 64];
    __shared__ alignas(16) short W2[64 * 256];
    __shared__ alignas(16) short Gi[16 * 64];
    __shared__ alignas(16) short Vs[16 * 64];
    __shared__ alignas(16) short Hd[16 * 256];
    __shared__ float B1s[256];
    const int bn = blockIdx.x;
    const int tid = threadIdx.x;
    const int w = tid >> 6, l = tid & 63;
    {
        const f32x4* s1 = (const f32x4*)w1t; f32x4* d1 = (f32x4*)W1;
        const f32x4* s2 = (const f32x4*)w2t; f32x4* d2 = (f32x4*)W2;
        #pragma unroll
        for (int i = 0; i < 8; i++) {
            d1[tid + i * 256] = s1[tid + i * 256];
            d2[tid + i * 256] = s2[tid + i * 256];
        }
    }
    B1s[tid] = b1v[tid];
    __syncthreads();
    const int col = l & 15, lg = l >> 4;
    for (int h = 0; h < H; h++) {
        {   // stage gin (swizzled) + val (linear), 2 KB each, all 256 threads
            const size_t base = (((size_t)bn * H) + h) * (KNN * DH);
            if (tid < 128)
                ((f32x4*)Gi)[tid] = ((const f32x4*)(gin_ws + base))[tid];
            else
                ((f32x4*)Vs)[tid - 128] = ((const f32x4*)(val_ws + base))[tid - 128];
        }
        __syncthreads();
        {   // GEMM1: Hd = relu(Gi @ ga_w1 + b1)
            const s16x8 a0 = *(const s16x8*)&Gi[(col << 6) + ((lg * 8) ^ ((col & 7) << 3))];
            const s16x8 a1 = *(const s16x8*)&Gi[(col << 6) + ((32 + lg * 8) ^ ((col & 7) << 3))];
            f32x4 acc[4];
            #pragma unroll
            for (int t = 0; t < 4; t++) acc[t] = f32x4{0.f, 0.f, 0.f, 0.f};
            #pragma unroll
            for (int t = 0; t < 4; t++) {
                const int n = (w << 6) + (t << 4) + col;
                const s16x8 bb0 = *(const s16x8*)&W1[(n << 6) + ((lg * 8) ^ ((n & 7) << 3))];
                const s16x8 bb1 = *(const s16x8*)&W1[(n << 6) + ((32 + lg * 8) ^ ((n & 7) << 3))];
                acc[t] = mfma16(a0, bb0, acc[t]);
                acc[t] = mfma16(a1, bb1, acc[t]);
            }
            #pragma unroll
            for (int t = 0; t < 4; t++) {
                const int n = (w << 6) + (t << 4) + col;
                const float bb = B1s[n];
                #pragma unroll
                for (int r = 0; r < 4; r++) {
                    const int kr = (lg << 2) + r;
                    Hd[(kr << 8) + (n ^ ((kr & 7) << 3))] = f2b(fmaxf(acc[t][r] + bb, 0.f));
                }
            }
        }
        __syncthreads();
        {   // GEMM2: logits = Hd @ ga_w2 + b2 ; softmax over K ; out
            f32x4 acc = f32x4{0.f, 0.f, 0.f, 0.f};
            const int d = (w << 4) + col;
            #pragma unroll
            for (int kt = 0; kt < 8; kt++) {
                const int el = kt * 32 + lg * 8;
                const s16x8 a  = *(const s16x8*)&Hd[(col << 8) + (el ^ ((col & 7) << 3))];
                const s16x8 bb = *(const s16x8*)&W2[(d << 8) + (el ^ ((d & 7) << 3))];
                acc = mfma16(a, bb, acc);
            }
            const float b2v = b2vv[d];
            float lgt[4];
            #pragma unroll
            for (int r = 0; r < 4; r++) lgt[r] = acc[r] + b2v;
            float mx = fmaxf(fmaxf(lgt[0], lgt[1]), fmaxf(lgt[2], lgt[3]));
            mx = fmaxf(mx, __shfl_xor(mx, 16));
            mx = fmaxf(mx, __shfl_xor(mx, 32));
            float p[4], s = 0.f;
            #pragma unroll
            for (int r = 0; r < 4; r++) { p[r] = expf(lgt[r] - mx); s += p[r]; }
            s += __shfl_xor(s, 16);
            s += __shfl_xor(s, 32);
            const float inv = 1.f / s;
            float o = 0.f;
            #pragma unroll
            for (int r = 0; r < 4; r++) {
                const int k = (lg << 2) + r;
                o += p[r] * b2f(Vs[(k << 6) + d]);
            }
            o *= inv;
            o += __shfl_xor(o, 16);
            o += __shfl_xor(o, 32);
            if (l < 16) attn_o[(size_t)bn * DM + h * DH + d] = o;
        }
        __syncthreads();
    }
}

// ---------------------------------------------------------------------------
// out = LN(a + res) * w + b  (row length DM=512, 256 threads x 2 floats)
__global__ __launch_bounds__(256) void k_ln(const float* __restrict__ a,
                                            const float* __restrict__ res,
                                            const float* __restrict__ wv,
                                            const float* __restrict__ bv,
                                            float* __restrict__ outp) {
    __shared__ float red[8];
    const int row = blockIdx.x, tid = threadIdx.x;
    const float2 va = ((const float2*)(a + (size_t)row * DM))[tid];
    const float2 vb = ((const float2*)(res + (size_t)row * DM))[tid];
    const float x0 = va.x + vb.x, x1 = va.y + vb.y;
    float s = x0 + x1;
    #pragma unroll
    for (int off = 32; off >= 1; off >>= 1) s += __shfl_xor(s, off);
    if ((tid & 63) == 0) red[tid >> 6] = s;
    __syncthreads();
    const float mean = (red[0] + red[1] + red[2] + red[3]) * (1.f / DM);
    const float d0 = x0 - mean, d1 = x1 - mean;
    float v = d0 * d0 + d1 * d1;
    #pragma unroll
    for (int off = 32; off >= 1; off >>= 1) v += __shfl_xor(v, off);
    if ((tid & 63) == 0) red[4 + (tid >> 6)] = v;
    __syncthreads();
    const float var = (red[4] + red[5] + red[6] + red[7]) * (1.f / DM);
    const float rstd = rsqrtf(var + 1e-5f);
    float2 o;
    o.x = d0 * rstd * wv[tid * 2 + 0] + bv[tid * 2 + 0];
    o.y = d1 * rstd * wv[tid * 2 + 1] + bv[tid * 2 + 1];
    ((float2*)(outp + (size_t)row * DM))[tid] = o;
}

// ---------------------------------------------------------------------------
extern "C" void kernel_launch(void* const* d_in, const int* in_sizes, int n_in,
                              void* d_out, int out_size, void* d_ws, size_t ws_size,
                              hipStream_t stream) {
    (void)in_sizes; (void)n_in; (void)out_size; (void)ws_size;
    const float* tgt     = (const float*)d_in[0];
    const float* src     = (const float*)d_in[1];
    const float* tgt_pos = (const float*)d_in[2];
    const float* src_pos = (const float*)d_in[3];
    const float* phi_w   = (const float*)d_in[4];
    const float* phi_b   = (const float*)d_in[5];
    const float* psi_w   = (const float*)d_in[6];
    const float* psi_b   = (const float*)d_in[7];
    const float* alpha_w = (const float*)d_in[8];
    const float* alpha_b = (const float*)d_in[9];
    const float* th_w1   = (const float*)d_in[10];
    const float* th_b1   = (const float*)d_in[11];
    const float* th_w2   = (const float*)d_in[12];
    const float* th_b2   = (const float*)d_in[13];
    const float* ga_w1   = (const float*)d_in[14];
    const float* ga_b1   = (const float*)d_in[15];
    const float* ga_w2   = (const float*)d_in[16];
    const float* ga_b2   = (const float*)d_in[17];
    const float* up_w    = (const float*)d_in[18];
    const float* up_b    = (const float*)d_in[19];
    const float* ln_w    = (const float*)d_in[20];
    const float* ln_b    = (const float*)d_in[21];
    const float* ffn_w1  = (const float*)d_in[22];
    const float* ffn_b1  = (const float*)d_in[23];
    const float* ffn_w2  = (const float*)d_in[24];
    const float* ffn_b2  = (const float*)d_in[25];
    const float* fln_w   = (const float*)d_in[26];
    const float* fln_b   = (const float*)d_in[27];
    float* outp = (float*)d_out;

    char* p = (char*)d_ws;
    auto alloc = [&](size_t bytes) { void* r = p; p += (bytes + 255) & ~(size_t)255; return r; };
    float* dotb    = (float*)alloc((size_t)B_ * NT * NS * 4);     // 32 MB
    float* snorm   = (float*)alloc((size_t)B_ * NS * 4);
    int*   idx     = (int*)alloc((size_t)B_ * NT * KNN * 4);
    float* sp_all  = (float*)alloc((size_t)B_ * NS * DM * 4);     // 16 MB
    float* pa_all  = (float*)alloc((size_t)B_ * NS * H * 128 * 4);// 32 MB
    float* phi_all = (float*)alloc((size_t)B_ * NT * DM * 4);     // 4 MB
    float* Wpa     = (float*)alloc(64 * 128 * 4);
    float* bias_pa = (float*)alloc(128 * 4);
    short* thw1t   = (short*)alloc(256 * 64 * 2);
    short* thw2t   = (short*)alloc(64 * 256 * 2);
    short* gaw1t   = (short*)alloc(256 * 64 * 2);
    short* gaw2t   = (short*)alloc(64 * 256 * 2);
    short* gin_ws  = (short*)alloc((size_t)B_ * NT * H * KNN * DH * 2); // 33.5 MB
    short* val_ws  = (short*)alloc((size_t)B_ * NT * H * KNN * DH * 2); // 33.5 MB
    float* attn_o  = (float*)alloc((size_t)B_ * NT * DM * 4);
    float* x_ws    = (float*)alloc((size_t)B_ * NT * DM * 4);
    float* hffn    = (float*)alloc((size_t)B_ * NT * DFF * 4);    // 16 MB
    float* ffn_o   = (float*)alloc((size_t)B_ * NT * DM * 4);

    k_norms<<<(B_ * NS) / 4, 256, 0, stream>>>(src, snorm, B_ * NS);
    k_sp<<<(B_ * NS * DM / 4) / 256, 256, 0, stream>>>(src_pos, up_w, up_b, sp_all);
    k_prep<<<289, 256, 0, stream>>>(psi_w, psi_b, alpha_w, alpha_b, th_w1, th_w2,
                                    ga_w1, ga_w2, Wpa, bias_pa, thw1t, thw2t, gaw1t, gaw2t);
    // dot = tgt . src^T  (per batch)
    k_gemm_f32<128, true, false, false><<<dim3(NS / 128, NT / 128, B_), 256, 0, stream>>>(
        tgt, DM, (long)NT * DM, src, DM, (long)NS * DM, dotb, NS, (long)NT * NS, nullptr, DM);
    k_topk<<<B_ * NT, 256, 0, stream>>>(dotb, snorm, idx);
    // pa_all = src_heads @ [psi_w | alpha_w] + [psi_b|alpha_b]   M = B*NS*H
    k_gemm_f32<128, false, false, true><<<dim3(1, (B_ * NS * H) / 128, 1), 256, 0, stream>>>(
        src, DH, 0, Wpa, 128, 0, pa_all, 128, 0, bias_pa, DH);
    // phi_all = tgt_heads @ phi_w + phi_b   M = B*NT*H
    k_gemm_f32<64, false, false, true><<<dim3(1, (B_ * NT * H) / 128, 1), 256, 0, stream>>>(
        tgt, DH, 0, phi_w, DH, 0, phi_all, DH, 0, phi_b, DH);
    k_delta<<<B_ * NT, 256, 0, stream>>>(tgt_pos, sp_all, phi_all, pa_all, idx,
                                         thw1t, thw2t, th_b1, th_b2, gin_ws, val_ws);
    k_gamma<<<B_ * NT, 256, 0, stream>>>(gin_ws, val_ws, gaw1t, gaw2t, ga_b1, ga_b2, attn_o);
    k_ln<<<B_ * NT, 256, 0, stream>>>(tgt, attn_o, ln_w, ln_b, x_ws);
    k_gemm_f32<128, false, true, true><<<dim3(DFF / 128, (B_ * NT) / 128, 1), 256, 0, stream>>>(
        x_ws, DM, 0, ffn_w1, DFF, 0, hffn, DFF, 0, ffn_b1, DM);
    k_gemm_f32<128, false, false, true><<<dim3(DM / 128, (B_ * NT) / 128, 1), 256, 0, stream>>>(
        hffn, DFF, 0, ffn_w2, DM, 0, ffn_o, DM, 0, ffn_b2, DFF);
    k_ln<<<B_ * NT, 256, 0, stream>>>(x_ws, ffn_o, fln_w, fln_b, outp);
}

// Round 9
// 526.783 us; speedup vs baseline: 1.5377x; 1.5377x over previous
//
#include <hip/hip_runtime.h>
#include <hip/hip_bf16.h>
#include <cfloat>

// ---------------------------------------------------------------------------
// CrossVectorAttentionEncoder on MI355X (gfx950)
//   k_norms   : ||src||^2 per (b,ns)  + src -> bf16 copy (for pa MFMA GEMM)
//   k_sp      : sp_all = src_pos @ up_src_w + up_src_b   (affine in 2 scalars)
//   k_prep    : pack biases, transpose+bf16(+swizzle / +hi/lo-split) weights
//   gemm(dot) : dot = tgt . src^T (fp32 -- exact-enough top-k ordering)
//   k_topk    : 16 smallest (snorm - 2*dot) per row -> idx
//   gemm(pa)  : MFMA bf16: pa_all = src_heads @ [psi_w|alpha_w] + bias
//   gemm(phi) : phi_all = tgt_heads @ phi_w + phi_b (fp32)
//   k_delta   : per (b,nt): MFMA MLP -> delta; emits gin/val (bf16)
//   k_gamma   : per (b,nt): MFMA MLP -> logits -> softmax K -> out
//   k_ln      : x = LN(tgt + out)  (+ hi/lo bf16 split of x for FFN1)
//   gemm x2   : FFN via MFMA split-bf16 (hi/lo 3-pass ~ fp32 accuracy)
//   k_ln      : out = LN(x + ffn)
// ---------------------------------------------------------------------------

#define DEVINL __device__ __forceinline__

constexpr int B_   = 2;
constexpr int NT   = 1024;
constexpr int NS   = 4096;
constexpr int DM   = 512;
constexpr int H    = 8;
constexpr int KNN  = 16;
constexpr int DH   = 64;
constexpr int DFF  = 2048;

typedef float f32x4 __attribute__((ext_vector_type(4)));
typedef short s16x8 __attribute__((ext_vector_type(8)));
typedef short s16x4 __attribute__((ext_vector_type(4)));

DEVINL short f2b(float f) {
    __hip_bfloat16 h = __float2bfloat16(f);
    short s; __builtin_memcpy(&s, &h, 2); return s;
}
DEVINL float b2f(short s) {
    __hip_bfloat16 h; __builtin_memcpy(&h, &s, 2); return __bfloat162float(h);
}
DEVINL f32x4 mfma16(s16x8 a, s16x8 b, f32x4 c) {
    return __builtin_amdgcn_mfma_f32_16x16x32_bf16(a, b, c, 0, 0, 0);
}

// ---------------------------------------------------------------------------
// ||row||^2 for rows of length DM; also emit bf16 copy of src. one wave/row.
__global__ __launch_bounds__(256) void k_norms(const float* __restrict__ x,
                                               float* __restrict__ nrm,
                                               short* __restrict__ xbf, int rows) {
    const int w = threadIdx.x >> 6, l = threadIdx.x & 63;
    const int row = blockIdx.x * 4 + w;
    if (row >= rows) return;
    const f32x4* p4 = (const f32x4*)(x + (size_t)row * DM);
    f32x4 v0 = p4[l], v1 = p4[l + 64];
    float acc = v0.x*v0.x + v0.y*v0.y + v0.z*v0.z + v0.w*v0.w
              + v1.x*v1.x + v1.y*v1.y + v1.z*v1.z + v1.w*v1.w;
    s16x4 h0, h1;
    h0[0] = f2b(v0.x); h0[1] = f2b(v0.y); h0[2] = f2b(v0.z); h0[3] = f2b(v0.w);
    h1[0] = f2b(v1.x); h1[1] = f2b(v1.y); h1[2] = f2b(v1.z); h1[3] = f2b(v1.w);
    *(s16x4*)&xbf[(size_t)row * DM + l * 4]       = h0;
    *(s16x4*)&xbf[(size_t)row * DM + 256 + l * 4] = h1;
    #pragma unroll
    for (int off = 32; off >= 1; off >>= 1) acc += __shfl_xor(acc, off);
    if (l == 0) nrm[row] = acc;
}

// ---------------------------------------------------------------------------
// sp_all[b][ns][c] = p0*W[0][c] + p1*W[1][c] + ub[c]
__global__ __launch_bounds__(256) void k_sp(const float* __restrict__ src_pos,
                                            const float* __restrict__ upw,
                                            const float* __restrict__ upb,
                                            float* __restrict__ sp) {
    const int i = blockIdx.x * 256 + threadIdx.x;  // f32x4 index
    if (i >= B_ * NS * DM / 4) return;
    const int c4 = i & (DM / 4 - 1);
    const int bn = i >> 7;
    const float p0 = src_pos[bn * 2 + 0], p1 = src_pos[bn * 2 + 1];
    f32x4 w0 = ((const f32x4*)upw)[c4];
    f32x4 w1 = ((const f32x4*)upw)[DM / 4 + c4];
    f32x4 ub = ((const f32x4*)upb)[c4];
    f32x4 r;
    r.x = p0 * w0.x + p1 * w1.x + ub.x;
    r.y = p0 * w0.y + p1 * w1.y + ub.y;
    r.z = p0 * w0.z + p1 * w1.z + ub.z;
    r.w = p0 * w0.w + p1 * w1.w + ub.w;
    ((f32x4*)sp)[i] = r;
}

// ---------------------------------------------------------------------------
// weight prep:
//  [0,8192)        Wpa_bf [128 n][64 k] bf16 = [psi_w|alpha_w]^T
//  [..,+128)       bias_pa
//  4 x 16384       th/ga MLP weights: transpose+bf16+XOR swizzle (as before)
//  +1048576        ffn_w1 -> w1t hi/lo bf16 [2048 n][512 k]
//  +1048576        ffn_w2 -> w2t hi/lo bf16 [512 n][2048 k]
__global__ __launch_bounds__(256) void k_prep(
    const float* __restrict__ psi_w, const float* __restrict__ psi_b,
    const float* __restrict__ alpha_w, const float* __restrict__ alpha_b,
    const float* __restrict__ th_w1, const float* __restrict__ th_w2,
    const float* __restrict__ ga_w1, const float* __restrict__ ga_w2,
    const float* __restrict__ ffn_w1, const float* __restrict__ ffn_w2,
    float* __restrict__ bias_pa,
    short* __restrict__ thw1t, short* __restrict__ thw2t,
    short* __restrict__ gaw1t, short* __restrict__ gaw2t,
    short* __restrict__ wpab,
    short* __restrict__ w1h, short* __restrict__ w1l,
    short* __restrict__ w2h, short* __restrict__ w2l) {
    long i = (long)blockIdx.x * 256 + threadIdx.x;
    if (i < 8192) { int n = i >> 6, k = i & 63;
        wpab[i] = f2b((n < 64) ? psi_w[k * 64 + n] : alpha_w[k * 64 + (n - 64)]); return; }
    i -= 8192;
    if (i < 128) { bias_pa[i] = (i < 64) ? psi_b[i] : alpha_b[i - 64]; return; }
    i -= 128;
    if (i < 16384) { int n = i >> 6, k = i & 63;
        thw1t[(n << 6) + (k ^ ((n & 7) << 3))] = f2b(th_w1[k * 256 + n]); return; }
    i -= 16384;
    if (i < 16384) { int n = i >> 8, k = i & 255;
        thw2t[(n << 8) + (k ^ ((n & 7) << 3))] = f2b(th_w2[k * 64 + n]); return; }
    i -= 16384;
    if (i < 16384) { int n = i >> 6, k = i & 63;
        gaw1t[(n << 6) + (k ^ ((n & 7) << 3))] = f2b(ga_w1[k * 256 + n]); return; }
    i -= 16384;
    if (i < 16384) { int n = i >> 8, k = i & 255;
        gaw2t[(n << 8) + (k ^ ((n & 7) << 3))] = f2b(ga_w2[k * 64 + n]); return; }
    i -= 16384;
    if (i < 1048576) {  // w1: src [512 k][2048 n] -> [n][k], coalesced read
        int k = i >> 11, n = i & 2047;
        float v = ffn_w1[(size_t)k * 2048 + n];
        short h = f2b(v);
        w1h[(size_t)n * 512 + k] = h;
        w1l[(size_t)n * 512 + k] = f2b(v - b2f(h));
        return;
    }
    i -= 1048576;
    if (i < 1048576) {  // w2: src [2048 k][512 n] -> [n][k]
        int k = i >> 9, n = i & 511;
        float v = ffn_w2[(size_t)k * 512 + n];
        short h = f2b(v);
        w2h[(size_t)n * 2048 + k] = h;
        w2l[(size_t)n * 2048 + k] = f2b(v - b2f(h));
        return;
    }
}

// ---------------------------------------------------------------------------
// fp32 GEMM (kept for dot + phi). BM=128, BK=16, BN in {64,128}.
template <int BN, bool TRANSB, bool RELU, bool HASBIAS>
__global__ __launch_bounds__(256) void k_gemm_f32(
    const float* __restrict__ A, int lda, long sA,
    const float* __restrict__ Bm, int ldb, long sB,
    float* __restrict__ C, int ldc, long sC,
    const float* __restrict__ bias, int K) {
    constexpr int BM = 128, BK = 16;
    constexpr int TN = BN / 16;
    __shared__ float As[BK][BM];
    __shared__ float Bs[BK][BN];
    A  += (size_t)blockIdx.z * sA;
    Bm += (size_t)blockIdx.z * sB;
    C  += (size_t)blockIdx.z * sC;
    const int m0 = blockIdx.y * BM, n0 = blockIdx.x * BN;
    const int tid = threadIdx.x, tm = tid >> 4, tn = tid & 15;
    float acc[8][TN];
    #pragma unroll
    for (int i = 0; i < 8; i++)
        #pragma unroll
        for (int j = 0; j < TN; j++) acc[i][j] = 0.f;

    for (int k0 = 0; k0 < K; k0 += BK) {
        {   // stage A (transposed): As[k][m]
            const int m = tid >> 1;
            #pragma unroll
            for (int i = 0; i < 2; i++) {
                const int kq = (tid & 1) * 2 + i;
                f32x4 v = *(const f32x4*)(A + (size_t)(m0 + m) * lda + k0 + kq * 4);
                As[kq * 4 + 0][m] = v.x; As[kq * 4 + 1][m] = v.y;
                As[kq * 4 + 2][m] = v.z; As[kq * 4 + 3][m] = v.w;
            }
        }
        if constexpr (TRANSB) {
            if constexpr (BN == 128) {
                const int n = tid >> 1;
                #pragma unroll
                for (int i = 0; i < 2; i++) {
                    const int kq = (tid & 1) * 2 + i;
                    f32x4 v = *(const f32x4*)(Bm + (size_t)(n0 + n) * ldb + k0 + kq * 4);
                    Bs[kq * 4 + 0][n] = v.x; Bs[kq * 4 + 1][n] = v.y;
                    Bs[kq * 4 + 2][n] = v.z; Bs[kq * 4 + 3][n] = v.w;
                }
            } else {
                const int n = tid >> 2, kq = tid & 3;
                f32x4 v = *(const f32x4*)(Bm + (size_t)(n0 + n) * ldb + k0 + kq * 4);
                Bs[kq * 4 + 0][n] = v.x; Bs[kq * 4 + 1][n] = v.y;
                Bs[kq * 4 + 2][n] = v.z; Bs[kq * 4 + 3][n] = v.w;
            }
        } else {
            if constexpr (BN == 128) {
                const int kr = tid >> 5, nq = tid & 31;
                #pragma unroll
                for (int i = 0; i < 2; i++)
                    *(f32x4*)&Bs[kr + i * 8][nq * 4] =
                        *(const f32x4*)(Bm + (size_t)(k0 + kr + i * 8) * ldb + n0 + nq * 4);
            } else {
                const int kr = tid >> 4, nq = tid & 15;
                *(f32x4*)&Bs[kr][nq * 4] =
                    *(const f32x4*)(Bm + (size_t)(k0 + kr) * ldb + n0 + nq * 4);
            }
        }
        __syncthreads();
        #pragma unroll
        for (int d = 0; d < BK; d++) {
            float ar[8], br[TN];
            *(f32x4*)&ar[0] = *(const f32x4*)&As[d][tm * 8];
            *(f32x4*)&ar[4] = *(const f32x4*)&As[d][tm * 8 + 4];
            *(f32x4*)&br[0] = *(const f32x4*)&Bs[d][tn * 4];
            if constexpr (TN == 8) *(f32x4*)&br[4] = *(const f32x4*)&Bs[d][64 + tn * 4];
            #pragma unroll
            for (int i = 0; i < 8; i++)
                #pragma unroll
                for (int j = 0; j < TN; j++)
                    acc[i][j] = fmaf(ar[i], br[j], acc[i][j]);
        }
        __syncthreads();
    }
    #pragma unroll
    for (int i = 0; i < 8; i++) {
        const int m = m0 + tm * 8 + i;
        float* crow = C + (size_t)m * ldc + n0;
        #pragma unroll
        for (int j = 0; j < TN; j++) {
            const int c = (TN == 8) ? ((j < 4) ? tn * 4 + j : 64 + tn * 4 + (j - 4))
                                    : tn * 4 + j;
            float v = acc[i][j];
            if constexpr (HASBIAS) v += bias[n0 + c];
            if constexpr (RELU) v = fmaxf(v, 0.f);
            acc[i][j] = v;
        }
        *(f32x4*)(crow + tn * 4) = *(f32x4*)&acc[i][0];
        if constexpr (TN == 8) *(f32x4*)(crow + 64 + tn * 4) = *(f32x4*)&acc[i][4];
    }
}

// ---------------------------------------------------------------------------
// bf16 MFMA GEMM, optionally hi/lo split (3-pass, ~fp32 accuracy).
// A: [M][K] bf16 (hi + optional lo), B: [N][K] bf16 pre-transposed (hi+lo).
// BM=64, BN=128, BK=64; 256 threads = 4 waves; wave -> 32x64 sub-tile.
// LDS rows are 64 bf16 = 128 B; XOR swizzle idx ^ ((row&7)<<3) (HW-proven
// pattern, same as k_delta/k_gamma).
template <bool SPLIT, bool OUTSPLIT, bool RELU, bool HASBIAS>
__global__ __launch_bounds__(256) void k_gemm_bf(
    const short* __restrict__ Ahg, const short* __restrict__ Alg, int lda,
    const short* __restrict__ Bhg, const short* __restrict__ Blg, int ldb,
    float* __restrict__ C, short* __restrict__ Chi, short* __restrict__ Clo, int ldc,
    const float* __restrict__ bias, int K) {
    constexpr int BM = 64, BN = 128, BK = 64;
    __shared__ alignas(16) short Ah[BM * BK];
    __shared__ alignas(16) short Bh[BN * BK];
    __shared__ alignas(16) short Al[SPLIT ? BM * BK : 8];
    __shared__ alignas(16) short Bl[SPLIT ? BN * BK : 8];
    const int tid = threadIdx.x;
    const int m0 = blockIdx.y * BM, n0 = blockIdx.x * BN;
    const int w = tid >> 6, l = tid & 63;
    const int wr = (w >> 1) * 32, wc = (w & 1) * 64;
    const int lrow = l & 15, lkg = l >> 4;
    const int ar = tid >> 2, aq = tid & 3;    // A staging: row, 16-elem quad
    const int bn_ = tid >> 1, bh2 = tid & 1;  // B staging: row, 32-elem half
    f32x4 acc[2][4];
    #pragma unroll
    for (int m = 0; m < 2; m++)
        #pragma unroll
        for (int nf = 0; nf < 4; nf++) acc[m][nf] = f32x4{0.f, 0.f, 0.f, 0.f};

    for (int k0 = 0; k0 < K; k0 += BK) {
        {   // stage A hi (+lo)
            const short* g = Ahg + (size_t)(m0 + ar) * lda + k0 + aq * 16;
            s16x8 v0 = *(const s16x8*)g, v1 = *(const s16x8*)(g + 8);
            *(s16x8*)&Ah[ar * 64 + ((aq * 16) ^ ((ar & 7) << 3))]     = v0;
            *(s16x8*)&Ah[ar * 64 + ((aq * 16 + 8) ^ ((ar & 7) << 3))] = v1;
            if constexpr (SPLIT) {
                const short* g2 = Alg + (size_t)(m0 + ar) * lda + k0 + aq * 16;
                s16x8 u0 = *(const s16x8*)g2, u1 = *(const s16x8*)(g2 + 8);
                *(s16x8*)&Al[ar * 64 + ((aq * 16) ^ ((ar & 7) << 3))]     = u0;
                *(s16x8*)&Al[ar * 64 + ((aq * 16 + 8) ^ ((ar & 7) << 3))] = u1;
            }
        }
        {   // stage B hi (+lo)
            const short* g = Bhg + (size_t)(n0 + bn_) * ldb + k0 + bh2 * 32;
            #pragma unroll
            for (int j = 0; j < 4; j++) {
                s16x8 v = *(const s16x8*)(g + j * 8);
                *(s16x8*)&Bh[bn_ * 64 + ((bh2 * 32 + j * 8) ^ ((bn_ & 7) << 3))] = v;
            }
            if constexpr (SPLIT) {
                const short* g2 = Blg + (size_t)(n0 + bn_) * ldb + k0 + bh2 * 32;
                #pragma unroll
                for (int j = 0; j < 4; j++) {
                    s16x8 v = *(const s16x8*)(g2 + j * 8);
                    *(s16x8*)&Bl[bn_ * 64 + ((bh2 * 32 + j * 8) ^ ((bn_ & 7) << 3))] = v;
                }
            }
        }
        __syncthreads();
        #pragma unroll
        for (int s = 0; s < 2; s++) {
            const int koff = s * 32 + lkg * 8;
            s16x8 af[2], bfh[4];
            #pragma unroll
            for (int m = 0; m < 2; m++) {
                const int row = wr + m * 16 + lrow;
                af[m] = *(const s16x8*)&Ah[row * 64 + (koff ^ ((row & 7) << 3))];
            }
            #pragma unroll
            for (int nf = 0; nf < 4; nf++) {
                const int row = wc + nf * 16 + lrow;
                bfh[nf] = *(const s16x8*)&Bh[row * 64 + (koff ^ ((row & 7) << 3))];
            }
            #pragma unroll
            for (int m = 0; m < 2; m++)
                #pragma unroll
                for (int nf = 0; nf < 4; nf++)
                    acc[m][nf] = mfma16(af[m], bfh[nf], acc[m][nf]);
            if constexpr (SPLIT) {
                s16x8 alf[2], blf[4];
                #pragma unroll
                for (int m = 0; m < 2; m++) {
                    const int row = wr + m * 16 + lrow;
                    alf[m] = *(const s16x8*)&Al[row * 64 + (koff ^ ((row & 7) << 3))];
                }
                #pragma unroll
                for (int nf = 0; nf < 4; nf++) {
                    const int row = wc + nf * 16 + lrow;
                    blf[nf] = *(const s16x8*)&Bl[row * 64 + (koff ^ ((row & 7) << 3))];
                }
                #pragma unroll
                for (int m = 0; m < 2; m++)
                    #pragma unroll
                    for (int nf = 0; nf < 4; nf++) {
                        acc[m][nf] = mfma16(af[m], blf[nf], acc[m][nf]);
                        acc[m][nf] = mfma16(alf[m], bfh[nf], acc[m][nf]);
                    }
            }
        }
        __syncthreads();
    }
    // epilogue: D col = l&15 (+frag), row = (l>>4)*4 + j  [m89 mapping]
    #pragma unroll
    for (int m = 0; m < 2; m++) {
        #pragma unroll
        for (int nf = 0; nf < 4; nf++) {
            const int col = n0 + wc + nf * 16 + lrow;
            float bv = 0.f;
            if constexpr (HASBIAS) bv = bias[col];
            #pragma unroll
            for (int j = 0; j < 4; j++) {
                const int row = m0 + wr + m * 16 + lkg * 4 + j;
                float v = acc[m][nf][j] + bv;
                if constexpr (RELU) v = fmaxf(v, 0.f);
                if constexpr (OUTSPLIT) {
                    short hh = f2b(v);
                    Chi[(size_t)row * ldc + col] = hh;
                    Clo[(size_t)row * ldc + col] = f2b(v - b2f(hh));
                } else {
                    C[(size_t)row * ldc + col] = v;
                }
            }
        }
    }
}

// ---------------------------------------------------------------------------
// top-16 smallest (snorm[n] - 2*dot[row][n]) per row. one block per row.
__global__ __launch_bounds__(256) void k_topk(const float* __restrict__ dotm,
                                              const float* __restrict__ snorm,
                                              int* __restrict__ idx_out) {
    __shared__ float vals[NS];
    __shared__ float wv_[4];
    __shared__ int   wi_[4];
    const int row = blockIdx.x;           // b*NT + m
    const int b = row >> 10;
    const int tid = threadIdx.x, l = tid & 63, w = tid >> 6;
    {
        const f32x4* d4 = (const f32x4*)(dotm + (size_t)row * NS);
        const f32x4* s4 = (const f32x4*)(snorm + (size_t)b * NS);
        #pragma unroll
        for (int t = 0; t < NS / 4 / 256; t++) {
            const int i = tid + t * 256;
            f32x4 dv = d4[i], sv = s4[i];
            f32x4 r;
            r.x = sv.x - 2.f * dv.x; r.y = sv.y - 2.f * dv.y;
            r.z = sv.z - 2.f * dv.z; r.w = sv.w - 2.f * dv.w;
            *(f32x4*)&vals[i * 4] = r;
        }
    }
    __syncthreads();
    for (int r = 0; r < KNN; r++) {
        float best = FLT_MAX; int bi = 0x7fffffff;
        #pragma unroll
        for (int t = 0; t < NS / 256; t++) {
            const int i = tid + t * 256;
            const float v = vals[i];
            if (v < best) { best = v; bi = i; }
        }
        #pragma unroll
        for (int off = 32; off >= 1; off >>= 1) {
            const float ov = __shfl_xor(best, off);
            const int   oi = __shfl_xor(bi, off);
            if (ov < best || (ov == best && oi < bi)) { best = ov; bi = oi; }
        }
        if (l == 0) { wv_[w] = best; wi_[w] = bi; }
        __syncthreads();
        if (tid == 0) {
            float bb = wv_[0]; int bbi = wi_[0];
            #pragma unroll
            for (int j = 1; j < 4; j++)
                if (wv_[j] < bb || (wv_[j] == bb && wi_[j] < bbi)) { bb = wv_[j]; bbi = wi_[j]; }
            idx_out[row * KNN + r] = bbi;
            vals[bbi] = FLT_MAX;
        }
        __syncthreads();
    }
}

// ---------------------------------------------------------------------------
// delta MLP per (b,nt). (unchanged from passing round-3 kernel)
__global__ __launch_bounds__(256) void k_delta(
    const float* __restrict__ tgt_pos, const float* __restrict__ sp_all,
    const float* __restrict__ phi_all, const float* __restrict__ pa_all,
    const int* __restrict__ idx_in,
    const short* __restrict__ w1t, const short* __restrict__ w2t,
    const float* __restrict__ b1v, const float* __restrict__ b2vv,
    short* __restrict__ gin_ws, short* __restrict__ val_ws) {
    __shared__ alignas(16) short W1[256 * 64];
    __shared__ alignas(16) short W2[64 * 256];
    __shared__ alignas(16) short Xd[16 * 64];
    __shared__ alignas(16) short Hd[16 * 256];
    __shared__ float B1s[256];
    __shared__ int sidx[16];
    const int bn = blockIdx.x;
    const int b = bn >> 10;
    const int tid = threadIdx.x;
    const int w = tid >> 6, l = tid & 63;
    {
        const f32x4* s1 = (const f32x4*)w1t; f32x4* d1 = (f32x4*)W1;
        const f32x4* s2 = (const f32x4*)w2t; f32x4* d2 = (f32x4*)W2;
        #pragma unroll
        for (int i = 0; i < 8; i++) {
            d1[tid + i * 256] = s1[tid + i * 256];
            d2[tid + i * 256] = s2[tid + i * 256];
        }
    }
    B1s[tid] = b1v[tid];
    if (tid < 16) sidx[tid] = idx_in[bn * KNN + tid];
    __syncthreads();
    const float* tp_row = tgt_pos + (size_t)bn * DM;
    const int col = l & 15, lg = l >> 4;
    for (int h = 0; h < H; h++) {
        {   // build Xd[16][64] = tp - sp, bf16, swizzled (vectorized)
            const int k = tid >> 4, e0 = (tid & 15) << 2;
            const float* sp_row = sp_all + ((size_t)(b * NS) + sidx[k]) * DM + h * DH;
            const f32x4 tpv = *(const f32x4*)(tp_row + h * DH + e0);
            const f32x4 spv = *(const f32x4*)(sp_row + e0);
            s16x4 o;
            o[0] = f2b(tpv.x - spv.x); o[1] = f2b(tpv.y - spv.y);
            o[2] = f2b(tpv.z - spv.z); o[3] = f2b(tpv.w - spv.w);
            *(s16x4*)&Xd[(k << 6) + (e0 ^ ((k & 7) << 3))] = o;
        }
        __syncthreads();                                   // (1)
        {   // GEMM1: Hd[16][256] = relu(Xd @ th_w1 + b1), bf16
            const s16x8 a0 = *(const s16x8*)&Xd[(col << 6) + ((lg * 8) ^ ((col & 7) << 3))];
            const s16x8 a1 = *(const s16x8*)&Xd[(col << 6) + ((32 + lg * 8) ^ ((col & 7) << 3))];
            f32x4 acc[4];
            #pragma unroll
            for (int t = 0; t < 4; t++) acc[t] = f32x4{0.f, 0.f, 0.f, 0.f};
            #pragma unroll
            for (int t = 0; t < 4; t++) {
                const int n = (w << 6) + (t << 4) + col;
                const s16x8 bb0 = *(const s16x8*)&W1[(n << 6) + ((lg * 8) ^ ((n & 7) << 3))];
                const s16x8 bb1 = *(const s16x8*)&W1[(n << 6) + ((32 + lg * 8) ^ ((n & 7) << 3))];
                acc[t] = mfma16(a0, bb0, acc[t]);
                acc[t] = mfma16(a1, bb1, acc[t]);
            }
            #pragma unroll
            for (int t = 0; t < 4; t++) {
                const int n = (w << 6) + (t << 4) + col;
                const float bb = B1s[n];
                #pragma unroll
                for (int r = 0; r < 4; r++) {
                    const int kr = (lg << 2) + r;
                    Hd[(kr << 8) + (n ^ ((kr & 7) << 3))] = f2b(fmaxf(acc[t][r] + bb, 0.f));
                }
            }
        }
        __syncthreads();                                   // (2)
        // GEMM2: delta[16][64] = Hd @ th_w2 + b2 ; gin/val staged in LDS
        f32x4 acc = f32x4{0.f, 0.f, 0.f, 0.f};
        const int n = (w << 4) + col;   // output channel d
        #pragma unroll
        for (int kt = 0; kt < 8; kt++) {
            const int el = kt * 32 + lg * 8;
            const s16x8 a  = *(const s16x8*)&Hd[(col << 8) + (el ^ ((col & 7) << 3))];
            const s16x8 bb = *(const s16x8*)&W2[(n << 8) + (el ^ ((n & 7) << 3))];
            acc = mfma16(a, bb, acc);
        }
        __syncthreads();                                   // (3) all Hd reads done
        {
            short* Gs = Hd;            // [16][64] swizzled gin  (2 KB)
            short* Vs = Hd + 1024;     // [16][64] linear   val  (2 KB)
            const float b2v = b2vv[n];
            const float phiv = phi_all[(size_t)bn * DM + h * DH + n];
            #pragma unroll
            for (int r = 0; r < 4; r++) {
                const int k = (lg << 2) + r;
                const float* pa = pa_all + (((size_t)(b * NS) + sidx[k]) * H + h) * 128;
                const float delta = acc[r] + b2v;
                Gs[(k << 6) + (n ^ ((k & 7) << 3))] = f2b(phiv - pa[n] + delta);
                Vs[(k << 6) + n] = f2b(pa[64 + n] + delta);
            }
        }
        __syncthreads();                                   // (4)
        {   // coalesced copy-out: 2 KB gin + 2 KB val per head
            const size_t obase = ((size_t)bn * H + h) * (KNN * DH); // in shorts
            if (tid < 128)
                ((f32x4*)(gin_ws + obase))[tid] = ((const f32x4*)Hd)[tid];
            else
                ((f32x4*)(val_ws + obase))[tid - 128] = ((const f32x4*)(Hd + 1024))[tid - 128];
        }
        __syncthreads();                                   // (5) = loop barrier
    }
}

// ---------------------------------------------------------------------------
// gamma MLP + softmax-over-K + weighted sum. one block per (b,nt). (unchanged)
__global__ __launch_bounds__(256) void k_gamma(
    const short* __restrict__ gin_ws, const short* __restrict__ val_ws,
    const short* __restrict__ w1t, const short* __restrict__ w2t,
    const float* __restrict__ b1v, const float* __restrict__ b2vv,
    float* __restrict__ attn_o) {
    __shared__ alignas(16) short W1[256 * 64];
    __shared__ alignas(16) short W2[64 * 256];
    __shared__ alignas(16) short Gi[16 * 64];
    __shared__ alignas(16) short Vs[16 * 64];
    __shared__ alignas(16) short Hd[16 * 256];
    __shared__ float B1s[256];
    const int bn = blockIdx.x;
    const int tid = threadIdx.x;
    const int w = tid >> 6, l = tid & 63;
    {
        const f32x4* s1 = (const f32x4*)w1t; f32x4* d1 = (f32x4*)W1;
        const f32x4* s2 = (const f32x4*)w2t; f32x4* d2 = (f32x4*)W2;
        #pragma unroll
        for (int i = 0; i < 8; i++) {
            d1[tid + i * 256] = s1[tid + i * 256];
            d2[tid + i * 256] = s2[tid + i * 256];
        }
    }
    B1s[tid] = b1v[tid];
    __syncthreads();
    const int col = l & 15, lg = l >> 4;
    for (int h = 0; h < H; h++) {
        {   // stage gin (swizzled) + val (linear), 2 KB each
            const size_t base = (((size_t)bn * H) + h) * (KNN * DH);
            if (tid < 128)
                ((f32x4*)Gi)[tid] = ((const f32x4*)(gin_ws + base))[tid];
            else
                ((f32x4*)Vs)[tid - 128] = ((const f32x4*)(val_ws + base))[tid - 128];
        }
        __syncthreads();
        {   // GEMM1: Hd = relu(Gi @ ga_w1 + b1)
            const s16x8 a0 = *(const s16x8*)&Gi[(col << 6) + ((lg * 8) ^ ((col & 7) << 3))];
            const s16x8 a1 = *(const s16x8*)&Gi[(col << 6) + ((32 + lg * 8) ^ ((col & 7) << 3))];
            f32x4 acc[4];
            #pragma unroll
            for (int t = 0; t < 4; t++) acc[t] = f32x4{0.f, 0.f, 0.f, 0.f};
            #pragma unroll
            for (int t = 0; t < 4; t++) {
                const int n = (w << 6) + (t << 4) + col;
                const s16x8 bb0 = *(const s16x8*)&W1[(n << 6) + ((lg * 8) ^ ((n & 7) << 3))];
                const s16x8 bb1 = *(const s16x8*)&W1[(n << 6) + ((32 + lg * 8) ^ ((n & 7) << 3))];
                acc[t] = mfma16(a0, bb0, acc[t]);
                acc[t] = mfma16(a1, bb1, acc[t]);
            }
            #pragma unroll
            for (int t = 0; t < 4; t++) {
                const int n = (w << 6) + (t << 4) + col;
                const float bb = B1s[n];
                #pragma unroll
                for (int r = 0; r < 4; r++) {
                    const int kr = (lg << 2) + r;
                    Hd[(kr << 8) + (n ^ ((kr & 7) << 3))] = f2b(fmaxf(acc[t][r] + bb, 0.f));
                }
            }
        }
        __syncthreads();
        {   // GEMM2: logits = Hd @ ga_w2 + b2 ; softmax over K ; out
            f32x4 acc = f32x4{0.f, 0.f, 0.f, 0.f};
            const int d = (w << 4) + col;
            #pragma unroll
            for (int kt = 0; kt < 8; kt++) {
                const int el = kt * 32 + lg * 8;
                const s16x8 a  = *(const s16x8*)&Hd[(col << 8) + (el ^ ((col & 7) << 3))];
                const s16x8 bb = *(const s16x8*)&W2[(d << 8) + (el ^ ((d & 7) << 3))];
                acc = mfma16(a, bb, acc);
            }
            const float b2v = b2vv[d];
            float lgt[4];
            #pragma unroll
            for (int r = 0; r < 4; r++) lgt[r] = acc[r] + b2v;
            float mx = fmaxf(fmaxf(lgt[0], lgt[1]), fmaxf(lgt[2], lgt[3]));
            mx = fmaxf(mx, __shfl_xor(mx, 16));
            mx = fmaxf(mx, __shfl_xor(mx, 32));
            float p[4], s = 0.f;
            #pragma unroll
            for (int r = 0; r < 4; r++) { p[r] = expf(lgt[r] - mx); s += p[r]; }
            s += __shfl_xor(s, 16);
            s += __shfl_xor(s, 32);
            const float inv = 1.f / s;
            float o = 0.f;
            #pragma unroll
            for (int r = 0; r < 4; r++) {
                const int k = (lg << 2) + r;
                o += p[r] * b2f(Vs[(k << 6) + d]);
            }
            o *= inv;
            o += __shfl_xor(o, 16);
            o += __shfl_xor(o, 32);
            if (l < 16) attn_o[(size_t)bn * DM + h * DH + d] = o;
        }
        __syncthreads();
    }
}

// ---------------------------------------------------------------------------
// out = LN(a + res) * w + b ; optional bf16 hi/lo split of out.
__global__ __launch_bounds__(256) void k_ln(const float* __restrict__ a,
                                            const float* __restrict__ res,
                                            const float* __restrict__ wv,
                                            const float* __restrict__ bv,
                                            float* __restrict__ outp,
                                            short* __restrict__ ohi,
                                            short* __restrict__ olo) {
    __shared__ float red[8];
    const int row = blockIdx.x, tid = threadIdx.x;
    const float2 va = ((const float2*)(a + (size_t)row * DM))[tid];
    const float2 vb = ((const float2*)(res + (size_t)row * DM))[tid];
    const float x0 = va.x + vb.x, x1 = va.y + vb.y;
    float s = x0 + x1;
    #pragma unroll
    for (int off = 32; off >= 1; off >>= 1) s += __shfl_xor(s, off);
    if ((tid & 63) == 0) red[tid >> 6] = s;
    __syncthreads();
    const float mean = (red[0] + red[1] + red[2] + red[3]) * (1.f / DM);
    const float d0 = x0 - mean, d1 = x1 - mean;
    float v = d0 * d0 + d1 * d1;
    #pragma unroll
    for (int off = 32; off >= 1; off >>= 1) v += __shfl_xor(v, off);
    if ((tid & 63) == 0) red[4 + (tid >> 6)] = v;
    __syncthreads();
    const float var = (red[4] + red[5] + red[6] + red[7]) * (1.f / DM);
    const float rstd = rsqrtf(var + 1e-5f);
    float2 o;
    o.x = d0 * rstd * wv[tid * 2 + 0] + bv[tid * 2 + 0];
    o.y = d1 * rstd * wv[tid * 2 + 1] + bv[tid * 2 + 1];
    ((float2*)(outp + (size_t)row * DM))[tid] = o;
    if (ohi) {
        const short h0 = f2b(o.x), h1 = f2b(o.y);
        ohi[(size_t)row * DM + tid * 2 + 0] = h0;
        ohi[(size_t)row * DM + tid * 2 + 1] = h1;
        olo[(size_t)row * DM + tid * 2 + 0] = f2b(o.x - b2f(h0));
        olo[(size_t)row * DM + tid * 2 + 1] = f2b(o.y - b2f(h1));
    }
}

// ---------------------------------------------------------------------------
extern "C" void kernel_launch(void* const* d_in, const int* in_sizes, int n_in,
                              void* d_out, int out_size, void* d_ws, size_t ws_size,
                              hipStream_t stream) {
    (void)in_sizes; (void)n_in; (void)out_size; (void)ws_size;
    const float* tgt     = (const float*)d_in[0];
    const float* src     = (const float*)d_in[1];
    const float* tgt_pos = (const float*)d_in[2];
    const float* src_pos = (const float*)d_in[3];
    const float* phi_w   = (const float*)d_in[4];
    const float* phi_b   = (const float*)d_in[5];
    const float* psi_w   = (const float*)d_in[6];
    const float* psi_b   = (const float*)d_in[7];
    const float* alpha_w = (const float*)d_in[8];
    const float* alpha_b = (const float*)d_in[9];
    const float* th_w1   = (const float*)d_in[10];
    const float* th_b1   = (const float*)d_in[11];
    const float* th_w2   = (const float*)d_in[12];
    const float* th_b2   = (const float*)d_in[13];
    const float* ga_w1   = (const float*)d_in[14];
    const float* ga_b1   = (const float*)d_in[15];
    const float* ga_w2   = (const float*)d_in[16];
    const float* ga_b2   = (const float*)d_in[17];
    const float* up_w    = (const float*)d_in[18];
    const float* up_b    = (const float*)d_in[19];
    const float* ln_w    = (const float*)d_in[20];
    const float* ln_b    = (const float*)d_in[21];
    const float* ffn_w1  = (const float*)d_in[22];
    const float* ffn_b1  = (const float*)d_in[23];
    const float* ffn_w2  = (const float*)d_in[24];
    const float* ffn_b2  = (const float*)d_in[25];
    const float* fln_w   = (const float*)d_in[26];
    const float* fln_b   = (const float*)d_in[27];
    float* outp = (float*)d_out;

    char* p = (char*)d_ws;
    auto alloc = [&](size_t bytes) { void* r = p; p += (bytes + 255) & ~(size_t)255; return r; };
    float* dotb    = (float*)alloc((size_t)B_ * NT * NS * 4);     // 32 MB
    float* snorm   = (float*)alloc((size_t)B_ * NS * 4);
    int*   idx     = (int*)alloc((size_t)B_ * NT * KNN * 4);
    float* sp_all  = (float*)alloc((size_t)B_ * NS * DM * 4);     // 16 MB
    float* pa_all  = (float*)alloc((size_t)B_ * NS * H * 128 * 4);// 32 MB
    float* phi_all = (float*)alloc((size_t)B_ * NT * DM * 4);     // 4 MB
    float* bias_pa = (float*)alloc(128 * 4);
    short* thw1t   = (short*)alloc(256 * 64 * 2);
    short* thw2t   = (short*)alloc(64 * 256 * 2);
    short* gaw1t   = (short*)alloc(256 * 64 * 2);
    short* gaw2t   = (short*)alloc(64 * 256 * 2);
    short* gin_ws  = (short*)alloc((size_t)B_ * NT * H * KNN * DH * 2); // 33.5 MB
    short* val_ws  = (short*)alloc((size_t)B_ * NT * H * KNN * DH * 2); // 33.5 MB
    float* attn_o  = (float*)alloc((size_t)B_ * NT * DM * 4);
    float* x_ws    = (float*)alloc((size_t)B_ * NT * DM * 4);
    short* src_hi  = (short*)alloc((size_t)B_ * NS * DM * 2);     // 8 MB
    short* wpab    = (short*)alloc(128 * 64 * 2);
    short* w1t_hi  = (short*)alloc((size_t)DM * DFF * 2);         // 2 MB
    short* w1t_lo  = (short*)alloc((size_t)DM * DFF * 2);
    short* w2t_hi  = (short*)alloc((size_t)DM * DFF * 2);
    short* w2t_lo  = (short*)alloc((size_t)DM * DFF * 2);
    // overlay (dotb is dead after k_topk): x hi/lo, hffn hi/lo, ffn_o = 24 MB
    short* x_hi    = (short*)dotb;                                // 2 MB
    short* x_lo    = x_hi + (size_t)B_ * NT * DM;                 // 2 MB
    short* hffn_hi = x_lo + (size_t)B_ * NT * DM;                 // 8 MB
    short* hffn_lo = hffn_hi + (size_t)B_ * NT * DFF;             // 8 MB
    float* ffn_o   = (float*)(hffn_lo + (size_t)B_ * NT * DFF);   // 4 MB

    k_norms<<<(B_ * NS) / 4, 256, 0, stream>>>(src, snorm, src_hi, B_ * NS);
    k_sp<<<(B_ * NS * DM / 4) / 256, 256, 0, stream>>>(src_pos, up_w, up_b, sp_all);
    k_prep<<<8481, 256, 0, stream>>>(psi_w, psi_b, alpha_w, alpha_b, th_w1, th_w2,
                                     ga_w1, ga_w2, ffn_w1, ffn_w2,
                                     bias_pa, thw1t, thw2t, gaw1t, gaw2t,
                                     wpab, w1t_hi, w1t_lo, w2t_hi, w2t_lo);
    // dot = tgt . src^T  (per batch, fp32)
    k_gemm_f32<128, true, false, false><<<dim3(NS / 128, NT / 128, B_), 256, 0, stream>>>(
        tgt, DM, (long)NT * DM, src, DM, (long)NS * DM, dotb, NS, (long)NT * NS, nullptr, DM);
    k_topk<<<B_ * NT, 256, 0, stream>>>(dotb, snorm, idx);
    // pa_all = src_heads @ [psi_w|alpha_w] + bias   (bf16 MFMA, M=B*NS*H)
    k_gemm_bf<false, false, false, true><<<dim3(1, (B_ * NS * H) / 64), 256, 0, stream>>>(
        src_hi, nullptr, DH, wpab, nullptr, DH, pa_all, nullptr, nullptr, 128, bias_pa, DH);
    // phi_all = tgt_heads @ phi_w + phi_b (fp32, small)
    k_gemm_f32<64, false, false, true><<<dim3(1, (B_ * NT * H) / 128, 1), 256, 0, stream>>>(
        tgt, DH, 0, phi_w, DH, 0, phi_all, DH, 0, phi_b, DH);
    k_delta<<<B_ * NT, 256, 0, stream>>>(tgt_pos, sp_all, phi_all, pa_all, idx,
                                         thw1t, thw2t, th_b1, th_b2, gin_ws, val_ws);
    k_gamma<<<B_ * NT, 256, 0, stream>>>(gin_ws, val_ws, gaw1t, gaw2t, ga_b1, ga_b2, attn_o);
    k_ln<<<B_ * NT, 256, 0, stream>>>(tgt, attn_o, ln_w, ln_b, x_ws, x_hi, x_lo);
    // FFN1: hffn = relu(x @ w1 + b1)  -> bf16 hi/lo   (split 3-pass MFMA)
    k_gemm_bf<true, true, true, true><<<dim3(DFF / 128, (B_ * NT) / 64), 256, 0, stream>>>(
        x_hi, x_lo, DM, w1t_hi, w1t_lo, DM, nullptr, hffn_hi, hffn_lo, DFF, ffn_b1, DM);
    // FFN2: ffn_o = hffn @ w2 + b2  (split 3-pass MFMA)
    k_gemm_bf<true, false, false, true><<<dim3(DM / 128, (B_ * NT) / 64), 256, 0, stream>>>(
        hffn_hi, hffn_lo, DFF, w2t_hi, w2t_lo, DFF, ffn_o, nullptr, nullptr, DM, ffn_b2, DFF);
    k_ln<<<B_ * NT, 256, 0, stream>>>(x_ws, ffn_o, fln_w, fln_b, outp, nullptr, nullptr);
}